// Round 13
// baseline (359.767 us; speedup 1.0000x reference)
//
#include <hip/hip_runtime.h>
#include <hip/hip_bf16.h>

// GCN: N=50000, E=800000, hidden 64, 5 convs (relu on first 4).
// f32 tensors, int32 edge_index, f32 d_out[N].  ws_size in [19.8, 26.0) MB.
// Round-12 evidence: VGPR_Count=40 -> compiler serialized the gather (one memory
// latency per edge, ~570 cyc/edge). This round: gather via global_load_lds DMA —
// per instruction 64 lanes fetch 2 full 128B rows into LDS (dest = uniform base +
// lane*4), vmcnt-tracked, no data VGPRs -> MLP independent of register allocator.
// Issue ceil(deg/2) DMAs, one s_waitcnt vmcnt(0), consume via stride-4 ds_read_b32,
// combine halves with shfl_xor(32). Rest (binned scatter, premult g, fused matmul)
// unchanged from round 12.
// Workspace (~18.6 MB): gA bf16[N*64] | gB bf16[N*64] | bucket u16[E] | staging u32[E]
//   | row_start i32[N+1] | cursor i32[N] | cnt i32[N] | dinv f32[N] | zg f32[N]
//   | bsum i32[257] | bcur i32[256]

#define TPB 256
#define EPT 8                    // edges per thread in k_bin
#define CHUNK (TPB * EPT)        // 2048 edges per block
typedef __hip_bfloat16 bf16;
#define B2F __bfloat162float

__device__ __forceinline__ float bflo(unsigned u) { return __uint_as_float(u << 16); }
__device__ __forceinline__ float bfhi(unsigned u) { return __uint_as_float(u & 0xffff0000u); }

__global__ void k_zero_cnt(int* __restrict__ cnt, int n) {
    int i = blockIdx.x * blockDim.x + threadIdx.x;
    if (i < n) cnt[i] = 0;
}

__global__ void k_hist(const int* __restrict__ dst, int* __restrict__ cnt, int E, int n) {
    int e = blockIdx.x * blockDim.x + threadIdx.x;
    if (e < E) {
        int d = dst[e];
        if ((unsigned)d < (unsigned)n) atomicAdd(&cnt[d], 1);
    }
}

__global__ void k_blocksum(const int* __restrict__ cnt, int* __restrict__ bsum, int n) {
    __shared__ int s[TPB];
    int i = blockIdx.x * TPB + threadIdx.x;
    s[threadIdx.x] = (i < n) ? cnt[i] : 0;
    __syncthreads();
    for (int off = TPB / 2; off > 0; off >>= 1) {
        if (threadIdx.x < off) s[threadIdx.x] += s[threadIdx.x + off];
        __syncthreads();
    }
    if (threadIdx.x == 0) bsum[blockIdx.x] = s[0];
}

__global__ void k_scan_bsum(int* __restrict__ bsum, int nb) {
    __shared__ int s[TPB];
    int t = threadIdx.x;
    int v = (t < nb) ? bsum[t] : 0;
    s[t] = v;
    __syncthreads();
    for (int off = 1; off < TPB; off <<= 1) {
        int u = (t >= off) ? s[t - off] : 0;
        __syncthreads();
        s[t] += u;
        __syncthreads();
    }
    if (t < nb) bsum[t] = s[t] - v;  // exclusive
}

__global__ void k_scan_final(const int* __restrict__ cnt, const int* __restrict__ bsum,
                             int* __restrict__ row_start, int* __restrict__ cursor,
                             float* __restrict__ dinv, int n) {
    __shared__ int s[TPB];
    int t = threadIdx.x;
    int i = blockIdx.x * TPB + t;
    int v = (i < n) ? cnt[i] : 0;
    s[t] = v;
    __syncthreads();
    for (int off = 1; off < TPB; off <<= 1) {
        int u = (t >= off) ? s[t - off] : 0;
        __syncthreads();
        s[t] += u;
        __syncthreads();
    }
    if (i < n) {
        int excl = bsum[blockIdx.x] + s[t] - v;
        row_start[i] = excl;
        cursor[i] = excl;
        dinv[i] = rsqrtf((float)v + 1.0f);   // +1 self-loop
        if (i == n - 1) row_start[n] = excl + v;
    }
}

// bcur[b] = CSR start of dst-bucket b (bucket = dst >> 8)
__global__ void k_init_bcur(const int* __restrict__ row_start, int* __restrict__ bcur,
                            int B, int n) {
    int b = threadIdx.x;
    if (b < B) bcur[b] = row_start[min(b << 8, n)];
}

// Pass 1: bin edges by dst>>8 into staging (record = src | (dst&255)<<16).
__global__ __launch_bounds__(TPB) void k_bin(
    const int* __restrict__ src, const int* __restrict__ dst,
    int* __restrict__ bcur, unsigned* __restrict__ staging, int E, int n) {
    __shared__ int hcnt[256];
    __shared__ int hbase[256];
    int tid = threadIdx.x;
    int e0 = blockIdx.x * CHUNK;
    hcnt[tid] = 0;
    __syncthreads();

    int eb[EPT];
    unsigned rec[EPT];
#pragma unroll
    for (int u = 0; u < EPT; ++u) {
        int e = e0 + u * TPB + tid;
        eb[u] = -1;
        if (e < E) {
            int d = dst[e], s = src[e];
            if ((unsigned)d < (unsigned)n && (unsigned)s < (unsigned)n) {
                eb[u] = d >> 8;
                rec[u] = (unsigned)s | ((unsigned)(d & 255) << 16);
                atomicAdd(&hcnt[eb[u]], 1);
            }
        }
    }
    __syncthreads();
    int c = hcnt[tid];
    hbase[tid] = (c > 0) ? atomicAdd(&bcur[tid], c) : 0;
    hcnt[tid] = 0;
    __syncthreads();
#pragma unroll
    for (int u = 0; u < EPT; ++u) {
        if (eb[u] >= 0) {
            int r = atomicAdd(&hcnt[eb[u]], 1);
            int pos = hbase[eb[u]] + r;
            if ((unsigned)pos < (unsigned)E) staging[pos] = rec[u];  // replay-safe
        }
    }
}

// Pass 2: one block per bucket; scatter staged records into the final u16 CSR region.
__global__ __launch_bounds__(TPB) void k_unbin(
    const unsigned* __restrict__ staging, const int* __restrict__ row_start,
    int* __restrict__ cursor, unsigned short* __restrict__ bucket, int E, int n) {
    int b = blockIdx.x;
    int lo = row_start[min(b << 8, n)];
    int hi = row_start[min((b + 1) << 8, n)];
    lo = max(0, min(lo, E)); hi = max(lo, min(hi, E));
    for (int i = lo + threadIdx.x; i < hi; i += TPB) {
        unsigned r = staging[i];
        int d = min((b << 8) + (int)(r >> 16), n - 1);
        int pos = atomicAdd(&cursor[d], 1);
        if ((unsigned)pos < (unsigned)E) bucket[pos] = (unsigned short)(r & 0xffffu);
    }
}

// g1[i][j] = (sum_{k<4} x[i][k] * W_in[k][j]) * dinv[i]   (premultiplied)
__global__ void k_mm_in(const float* __restrict__ x, const float* __restrict__ W,
                        const float* __restrict__ dinv, bf16* __restrict__ g, int n) {
    int t = blockIdx.x * blockDim.x + threadIdx.x;
    if (t >= n * 64) return;
    int i = t >> 6, j = t & 63;
    float acc = 0.f;
#pragma unroll
    for (int k = 0; k < 4; ++k) acc = fmaf(x[i * 4 + k], W[k * 64 + j], acc);
    g[t] = __float2bfloat16(acc * dinv[i]);
}

// DMA gather-aggregate: per global_load_lds instruction, 64 lanes fetch TWO full
// 128B rows (lane l: row of edge 2t+(l>>5), word l&31) into the wave's LDS buffer
// at base + l*4. Issue ceil(cnt/2) DMAs, wait vmcnt(0), consume via stride-4
// ds_read_b32 (conflict-free), combine parity halves with shfl_xor(32).
// Result row (64 floats) written to sVrow by lanes 0..31 as float2.
__device__ __forceinline__ void agg_row_dma(const bf16* __restrict__ g,
                                            const unsigned short* __restrict__ bucket,
                                            int k0, int k1, int d,
                                            char* __restrict__ bufw,  // 2KB, wave-private
                                            float* __restrict__ sVrow,
                                            int lane, unsigned nm1, unsigned Em1) {
    int h = lane >> 5, w = lane & 31;
    // self term (accumulate in half 0 only; both halves load, harmless)
    unsigned us = *(const unsigned*)((const char*)g + (size_t)d * 128 + 4 * w);
    float ax = 0.f, ay = 0.f;
    if (h == 0) { ax += bflo(us); ay += bfhi(us); }
    for (int base = k0; base < k1; base += 64) {
        int bcnt = min(64, k1 - base);
        int rec = bucket[min((unsigned)(base + lane), Em1)];   // coalesced u16 load
        for (int c = 0; c < bcnt; c += 16) {
            int ccnt = min(16, bcnt - c);
            int tcount = (ccnt + 1) >> 1;                      // <=8 DMAs in flight
            for (int t = 0; t < tcount; ++t) {
                int idx = c + 2 * t + h;                       // edge slot for this half
                unsigned s = min((unsigned)__shfl(rec, min(idx, 63)), nm1);
                const char* gp = (const char*)g + (size_t)s * 128 + 4 * w;
                __builtin_amdgcn_global_load_lds(
                    (const __attribute__((address_space(1))) void*)gp,
                    (__attribute__((address_space(3))) void*)(bufw + t * 256),
                    4, 0, 0);
            }
            __builtin_amdgcn_s_waitcnt(0x0f70);                // vmcnt(0)
            for (int t = 0; t < tcount; ++t) {
                unsigned u = *(const unsigned*)(bufw + t * 256 + 4 * lane);
                int e = base + c + 2 * t + h;
                if (e < k1) { ax += bflo(u); ay += bfhi(u); }
            }
        }
    }
    ax += __shfl_xor(ax, 32);
    ay += __shfl_xor(ay, 32);
    if (h == 0) ((float2*)sVrow)[w] = make_float2(ax, ay);
}

// Fused layer: one wave per node (4 nodes/block). DMA aggregation -> wave-local LDS
// row; a = relu(dd*sum+bias); gOut = (a @ W) * dd with W staged in LDS (one barrier).
__global__ __launch_bounds__(TPB) void k_gconv(
    const bf16* __restrict__ gIn, const float* __restrict__ dinv,
    const int* __restrict__ row_start, const unsigned short* __restrict__ bucket,
    const float* __restrict__ bias, const float* __restrict__ W,
    bf16* __restrict__ gOut, int n, int E) {
    __shared__ float sW[64 * 64];
    __shared__ unsigned sBuf[4][512];    // 2KB per wave DMA buffer
    __shared__ float sV[4][64];
    int tid = threadIdx.x;
    for (int k = tid; k < 1024; k += TPB) ((float4*)sW)[k] = ((const float4*)W)[k];
    __syncthreads();                      // sW ready (only block-wide barrier)
    int r = tid >> 6, j = tid & 63;
    int d = blockIdx.x * 4 + r;
    if (d >= n) return;                   // wave-uniform
    float dd = dinv[d];
    int k0 = row_start[d], k1 = row_start[d + 1];
    k1 = min(k1, E); k0 = max(min(k0, k1), 0);
    agg_row_dma(gIn, bucket, k0, k1, d, (char*)sBuf[r], sV[r], j,
                (unsigned)(n - 1), (unsigned)(E - 1));
    // wave-local LDS ordering (lgkmcnt) — no barrier
    float a = fmaxf(fmaf(dd, sV[r][j], bias[j]), 0.f);
    sV[r][j] = a;
    const float4* ap = (const float4*)&sV[r][0];
    float acc = 0.f;
#pragma unroll
    for (int k4 = 0; k4 < 16; ++k4) {
        float4 a4 = ap[k4];               // wave-uniform address -> broadcast b128
        acc = fmaf(a4.x, sW[(4 * k4 + 0) * 64 + j], acc);
        acc = fmaf(a4.y, sW[(4 * k4 + 1) * 64 + j], acc);
        acc = fmaf(a4.z, sW[(4 * k4 + 2) * 64 + j], acc);
        acc = fmaf(a4.w, sW[(4 * k4 + 3) * 64 + j], acc);
    }
    gOut[(size_t)d * 64 + j] = __float2bfloat16(acc * dd);
}

// Last hidden conv fused with 64->1 matmul: zg[d] = (relu(dd*sum+b) . Wout) * dd.
__global__ __launch_bounds__(TPB) void k_gconv_z(
    const bf16* __restrict__ gIn, const float* __restrict__ dinv,
    const int* __restrict__ row_start, const unsigned short* __restrict__ bucket,
    const float* __restrict__ bias, const float* __restrict__ Wout,
    float* __restrict__ zg, int n, int E) {
    __shared__ unsigned sBuf[4][512];
    __shared__ float sV[4][64];
    int tid = threadIdx.x;
    int r = tid >> 6, j = tid & 63;
    int d = blockIdx.x * 4 + r;
    if (d >= n) return;                   // wave-uniform
    float dd = dinv[d];
    int k0 = row_start[d], k1 = row_start[d + 1];
    k1 = min(k1, E); k0 = max(min(k0, k1), 0);
    agg_row_dma(gIn, bucket, k0, k1, d, (char*)sBuf[r], sV[r], j,
                (unsigned)(n - 1), (unsigned)(E - 1));
    float a = fmaxf(fmaf(dd, sV[r][j], bias[j]), 0.f) * Wout[j];
#pragma unroll
    for (int off = 32; off > 0; off >>= 1) a += __shfl_down(a, off);
    if (j == 0) zg[d] = a * dd;
}

// out[d] = dd*(zg[d] + sum zg[s]) + b_out.  One wave per node, lane = neighbor.
__global__ __launch_bounds__(TPB) void k_out(
    const float* __restrict__ zg, const float* __restrict__ dinv,
    const int* __restrict__ row_start, const unsigned short* __restrict__ bucket,
    const float* __restrict__ b_out, float* __restrict__ out, int n, int E) {
    int t = blockIdx.x * blockDim.x + threadIdx.x;
    int d = t >> 6, lane = t & 63;
    if (d >= n) return;
    int k0 = row_start[d], k1 = row_start[d + 1];
    k1 = min(k1, E); k0 = max(min(k0, k1), 0);
    unsigned nm1 = (unsigned)(n - 1);
    float v = 0.f;
    for (int k = k0 + lane; k < k1; k += 64) {
        unsigned s = min((unsigned)bucket[k], nm1);
        v += zg[s];
    }
#pragma unroll
    for (int off = 32; off > 0; off >>= 1) v += __shfl_down(v, off);
    if (lane == 0) out[d] = fmaf(zg[d] + v, dinv[d], b_out[0]);
}

extern "C" void kernel_launch(void* const* d_in, const int* in_sizes, int n_in,
                              void* d_out, int out_size, void* d_ws, size_t ws_size,
                              hipStream_t stream) {
    const float* x     = (const float*)d_in[0];
    const int*   ei    = (const int*)d_in[1];
    const float* W_in  = (const float*)d_in[2];
    const float* b_in  = (const float*)d_in[3];
    const float* W_h   = (const float*)d_in[4];
    const float* b_h   = (const float*)d_in[5];
    const float* W_out = (const float*)d_in[6];
    const float* b_out = (const float*)d_in[7];
    float* out = (float*)d_out;

    int N = in_sizes[0] / 4;
    int E = in_sizes[1] / 2;
    const int* src = ei;
    const int* dst = ei + E;

    char* ws = (char*)d_ws;
    bf16* gA               = (bf16*)ws;           ws += (size_t)N * 64 * 2;
    bf16* gB               = (bf16*)ws;           ws += (size_t)N * 64 * 2;
    unsigned short* bucket = (unsigned short*)ws; ws += (size_t)E * 2;
    unsigned* staging      = (unsigned*)ws;       ws += (size_t)E * 4;
    int*  row_start        = (int*)ws;            ws += (size_t)(N + 1) * 4;
    int*  cursor           = (int*)ws;            ws += (size_t)N * 4;
    int*  cnt              = (int*)ws;            ws += (size_t)N * 4;
    float* dinv            = (float*)ws;          ws += (size_t)N * 4;
    float* zg              = (float*)ws;          ws += (size_t)N * 4;
    int*  bsum             = (int*)ws;            ws += 257 * 4;
    int*  bcur             = (int*)ws;            // 256 ints

    int B   = (N + 255) >> 8;            // dst buckets (196 for N=50000; <=256)
    int gN  = (N + TPB - 1) / TPB;       // scan chunk count (<=256 for N<=65536)
    int gE  = (E + TPB - 1) / TPB;
    int gNF = (N * 64 + TPB - 1) / TPB;
    int gN4 = (N + 3) / 4;               // 4 nodes/block (1 wave per node)
    int gBin = (E + CHUNK - 1) / CHUNK;  // 391

    // ---- CSR build + norms ----
    k_zero_cnt<<<gN, TPB, 0, stream>>>(cnt, N);
    k_hist<<<gE, TPB, 0, stream>>>(dst, cnt, E, N);
    k_blocksum<<<gN, TPB, 0, stream>>>(cnt, bsum, N);
    k_scan_bsum<<<1, TPB, 0, stream>>>(bsum, gN);
    k_scan_final<<<gN, TPB, 0, stream>>>(cnt, bsum, row_start, cursor, dinv, N);
    k_init_bcur<<<1, TPB, 0, stream>>>(row_start, bcur, B, N);
    k_bin<<<gBin, TPB, 0, stream>>>(src, dst, bcur, staging, E, N);
    k_unbin<<<B, TPB, 0, stream>>>(staging, row_start, cursor, bucket, E, N);

    // ---- layers (feature buffers premultiplied by dinv) ----
    k_mm_in<<<gNF, TPB, 0, stream>>>(x, W_in, dinv, gA, N);
    k_gconv<<<gN4, TPB, 0, stream>>>(gA, dinv, row_start, bucket, b_in, W_h, gB, N, E);
    k_gconv<<<gN4, TPB, 0, stream>>>(gB, dinv, row_start, bucket, b_h, W_h + 4096, gA, N, E);
    k_gconv<<<gN4, TPB, 0, stream>>>(gA, dinv, row_start, bucket, b_h + 64, W_h + 8192, gB, N, E);
    k_gconv_z<<<gN4, TPB, 0, stream>>>(gB, dinv, row_start, bucket, b_h + 128, W_out, zg, N, E);
    k_out<<<gN4, TPB, 0, stream>>>(zg, dinv, row_start, bucket, b_out, out, N, E);
}

// Round 14
// 310.379 us; speedup vs baseline: 1.1591x; 1.1591x over previous
//
#include <hip/hip_runtime.h>
#include <hip/hip_bf16.h>

// GCN: N=50000, E=800000, hidden 64, 5 convs (relu on first 4).
// f32 tensors, int32 edge_index, f32 d_out[N].  ws_size in [19.8, 26.0) MB.
// Round-13 post-mortem: DMA gather regressed (vmcnt(0) drain every 16 edges).
// Reverted to round-11 (310 us best: quad gather + binned scatter). This round's
// single change: NO sW LDS staging — W (16 KB) is L1-resident (32 KB/CU) since all
// blocks read it identically; matmul reads W from global with 4 partial accs.
// LDS/block 20.5 -> 4 KB => 8 blocks/CU (wave-slot bound, 32 waves/CU) and zero
// barriers. Gather critical path (~2000 cyc) now covered by ~2x resident waves.
// Workspace (~18.6 MB): gA bf16[N*64] | gB bf16[N*64] | bucket u16[E] | staging u32[E]
//   | row_start i32[N+1] | cursor i32[N] | cnt i32[N] | dinv f32[N] | zg f32[N]
//   | bsum i32[257] | bcur i32[256]

#define TPB 256
#define EPT 8                    // edges per thread in k_bin
#define CHUNK (TPB * EPT)        // 2048 edges per block
typedef __hip_bfloat16 bf16;
#define B2F __bfloat162float

__global__ void k_zero_cnt(int* __restrict__ cnt, int n) {
    int i = blockIdx.x * blockDim.x + threadIdx.x;
    if (i < n) cnt[i] = 0;
}

__global__ void k_hist(const int* __restrict__ dst, int* __restrict__ cnt, int E, int n) {
    int e = blockIdx.x * blockDim.x + threadIdx.x;
    if (e < E) {
        int d = dst[e];
        if ((unsigned)d < (unsigned)n) atomicAdd(&cnt[d], 1);
    }
}

__global__ void k_blocksum(const int* __restrict__ cnt, int* __restrict__ bsum, int n) {
    __shared__ int s[TPB];
    int i = blockIdx.x * TPB + threadIdx.x;
    s[threadIdx.x] = (i < n) ? cnt[i] : 0;
    __syncthreads();
    for (int off = TPB / 2; off > 0; off >>= 1) {
        if (threadIdx.x < off) s[threadIdx.x] += s[threadIdx.x + off];
        __syncthreads();
    }
    if (threadIdx.x == 0) bsum[blockIdx.x] = s[0];
}

__global__ void k_scan_bsum(int* __restrict__ bsum, int nb) {
    __shared__ int s[TPB];
    int t = threadIdx.x;
    int v = (t < nb) ? bsum[t] : 0;
    s[t] = v;
    __syncthreads();
    for (int off = 1; off < TPB; off <<= 1) {
        int u = (t >= off) ? s[t - off] : 0;
        __syncthreads();
        s[t] += u;
        __syncthreads();
    }
    if (t < nb) bsum[t] = s[t] - v;  // exclusive
}

__global__ void k_scan_final(const int* __restrict__ cnt, const int* __restrict__ bsum,
                             int* __restrict__ row_start, int* __restrict__ cursor,
                             float* __restrict__ dinv, int n) {
    __shared__ int s[TPB];
    int t = threadIdx.x;
    int i = blockIdx.x * TPB + t;
    int v = (i < n) ? cnt[i] : 0;
    s[t] = v;
    __syncthreads();
    for (int off = 1; off < TPB; off <<= 1) {
        int u = (t >= off) ? s[t - off] : 0;
        __syncthreads();
        s[t] += u;
        __syncthreads();
    }
    if (i < n) {
        int excl = bsum[blockIdx.x] + s[t] - v;
        row_start[i] = excl;
        cursor[i] = excl;
        dinv[i] = rsqrtf((float)v + 1.0f);   // +1 self-loop
        if (i == n - 1) row_start[n] = excl + v;
    }
}

// bcur[b] = CSR start of dst-bucket b (bucket = dst >> 8)
__global__ void k_init_bcur(const int* __restrict__ row_start, int* __restrict__ bcur,
                            int B, int n) {
    int b = threadIdx.x;
    if (b < B) bcur[b] = row_start[min(b << 8, n)];
}

// Pass 1: bin edges by dst>>8 into staging (record = src | (dst&255)<<16).
__global__ __launch_bounds__(TPB) void k_bin(
    const int* __restrict__ src, const int* __restrict__ dst,
    int* __restrict__ bcur, unsigned* __restrict__ staging, int E, int n) {
    __shared__ int hcnt[256];
    __shared__ int hbase[256];
    int tid = threadIdx.x;
    int e0 = blockIdx.x * CHUNK;
    hcnt[tid] = 0;
    __syncthreads();

    int eb[EPT];
    unsigned rec[EPT];
#pragma unroll
    for (int u = 0; u < EPT; ++u) {
        int e = e0 + u * TPB + tid;
        eb[u] = -1;
        if (e < E) {
            int d = dst[e], s = src[e];
            if ((unsigned)d < (unsigned)n && (unsigned)s < (unsigned)n) {
                eb[u] = d >> 8;
                rec[u] = (unsigned)s | ((unsigned)(d & 255) << 16);
                atomicAdd(&hcnt[eb[u]], 1);
            }
        }
    }
    __syncthreads();
    int c = hcnt[tid];
    hbase[tid] = (c > 0) ? atomicAdd(&bcur[tid], c) : 0;
    hcnt[tid] = 0;
    __syncthreads();
#pragma unroll
    for (int u = 0; u < EPT; ++u) {
        if (eb[u] >= 0) {
            int r = atomicAdd(&hcnt[eb[u]], 1);
            int pos = hbase[eb[u]] + r;
            if ((unsigned)pos < (unsigned)E) staging[pos] = rec[u];  // replay-safe
        }
    }
}

// Pass 2: one block per bucket; scatter staged records into the final u16 CSR region.
__global__ __launch_bounds__(TPB) void k_unbin(
    const unsigned* __restrict__ staging, const int* __restrict__ row_start,
    int* __restrict__ cursor, unsigned short* __restrict__ bucket, int E, int n) {
    int b = blockIdx.x;
    int lo = row_start[min(b << 8, n)];
    int hi = row_start[min((b + 1) << 8, n)];
    lo = max(0, min(lo, E)); hi = max(lo, min(hi, E));
    for (int i = lo + threadIdx.x; i < hi; i += TPB) {
        unsigned r = staging[i];
        int d = min((b << 8) + (int)(r >> 16), n - 1);
        int pos = atomicAdd(&cursor[d], 1);
        if ((unsigned)pos < (unsigned)E) bucket[pos] = (unsigned short)(r & 0xffffu);
    }
}

// g1[i][j] = (sum_{k<4} x[i][k] * W_in[k][j]) * dinv[i]   (premultiplied)
__global__ void k_mm_in(const float* __restrict__ x, const float* __restrict__ W,
                        const float* __restrict__ dinv, bf16* __restrict__ g, int n) {
    int t = blockIdx.x * blockDim.x + threadIdx.x;
    if (t >= n * 64) return;
    int i = t >> 6, j = t & 63;
    float acc = 0.f;
#pragma unroll
    for (int k = 0; k < 4; ++k) acc = fmaf(x[i * 4 + k], W[k * 64 + j], acc);
    g[t] = __float2bfloat16(acc * dinv[i]);
}

__device__ __forceinline__ void acc_quad(float4& a, uint2 w) {
    a.x += __uint_as_float(w.x << 16);
    a.y += __uint_as_float(w.x & 0xffff0000u);
    a.z += __uint_as_float(w.y << 16);
    a.w += __uint_as_float(w.y & 0xffff0000u);
}

// Quad gather: 4 edges per load instruction; lane group g=lane>>4 takes edge k+g,
// lane i=lane&15 loads uint2 = 4 packed bf16 feats. Each group writes its float4
// partial to its own LDS row; the (same-wave) transform sums the 4 rows.
__device__ __forceinline__ void agg_row_quad(const bf16* __restrict__ g,
                                             const unsigned short* __restrict__ bucket,
                                             int k0, int k1, int d, float* __restrict__ sVp,
                                             int lane, unsigned nm1, unsigned Em1) {
    int grp = lane >> 4, i = lane & 15;
    float4 a = {0.f, 0.f, 0.f, 0.f};
    if (grp == 0) {  // self term
        uint2 w = *(const uint2*)(g + (size_t)d * 64 + 4 * i);
        acc_quad(a, w);
    }
    for (int base = k0; base < k1; base += 64) {
        int cnt = min(64, k1 - base);
        int rec = bucket[min((unsigned)(base + lane), Em1)];  // coalesced u16 load
        int k = 0;
        for (; k + 16 <= cnt; k += 16) {                      // 16 edges, 4 quad loads
            unsigned s0 = min((unsigned)__shfl(rec, k + 0 + grp), nm1);
            unsigned s1 = min((unsigned)__shfl(rec, k + 4 + grp), nm1);
            unsigned s2 = min((unsigned)__shfl(rec, k + 8 + grp), nm1);
            unsigned s3 = min((unsigned)__shfl(rec, k + 12 + grp), nm1);
            uint2 w0 = *(const uint2*)(g + (size_t)s0 * 64 + 4 * i);
            uint2 w1 = *(const uint2*)(g + (size_t)s1 * 64 + 4 * i);
            uint2 w2 = *(const uint2*)(g + (size_t)s2 * 64 + 4 * i);
            uint2 w3 = *(const uint2*)(g + (size_t)s3 * 64 + 4 * i);
            acc_quad(a, w0); acc_quad(a, w1); acc_quad(a, w2); acc_quad(a, w3);
        }
        for (; k < cnt; k += 4) {                             // tail, predicated
            int e = k + grp;
            unsigned s = min((unsigned)__shfl(rec, min(e, 63)), nm1);
            uint2 w = *(const uint2*)(g + (size_t)s * 64 + 4 * i);
            if (e < cnt) acc_quad(a, w);
        }
    }
    ((float4*)(sVp + grp * 64))[i] = a;   // partial row per group (wave-local)
}

// Fused layer: one wave per node (4 nodes/block). NO LDS W tile, NO barriers:
// W is read from global (L1-resident: 16 KB, identical across blocks); sVp is
// wave-local. LDS/block = 4 KB -> 8 blocks/CU (wave-slot bound).
__global__ __launch_bounds__(TPB) void k_gconv(
    const bf16* __restrict__ gIn, const float* __restrict__ dinv,
    const int* __restrict__ row_start, const unsigned short* __restrict__ bucket,
    const float* __restrict__ bias, const float* __restrict__ W,
    bf16* __restrict__ gOut, int n, int E) {
    __shared__ float sVp[4][4 * 64];     // [wave][group][64]
    int tid = threadIdx.x;
    int r = tid >> 6, j = tid & 63;
    int d = blockIdx.x * 4 + r;
    if (d >= n) return;                   // wave-uniform
    float dd = dinv[d];
    int k0 = row_start[d], k1 = row_start[d + 1];
    k1 = min(k1, E); k0 = max(min(k0, k1), 0);
    agg_row_quad(gIn, bucket, k0, k1, d, sVp[r], j, (unsigned)(n - 1), (unsigned)(E - 1));
    // wave-local LDS ordering (lgkmcnt) — no barrier needed
    float v = sVp[r][j] + sVp[r][64 + j] + sVp[r][128 + j] + sVp[r][192 + j];
    float a = fmaxf(fmaf(dd, v, bias[j]), 0.f);
    sVp[r][j] = a;                        // row 0 holds the activation (wave-local)
    const float4* ap = (const float4*)&sVp[r][0];
    float acc0 = 0.f, acc1 = 0.f, acc2 = 0.f, acc3 = 0.f;
#pragma unroll
    for (int k4 = 0; k4 < 16; ++k4) {
        float4 a4 = ap[k4];               // wave-uniform address -> broadcast b128
        acc0 = fmaf(a4.x, W[(4 * k4 + 0) * 64 + j], acc0);
        acc1 = fmaf(a4.y, W[(4 * k4 + 1) * 64 + j], acc1);
        acc2 = fmaf(a4.z, W[(4 * k4 + 2) * 64 + j], acc2);
        acc3 = fmaf(a4.w, W[(4 * k4 + 3) * 64 + j], acc3);
    }
    float acc = (acc0 + acc1) + (acc2 + acc3);
    gOut[(size_t)d * 64 + j] = __float2bfloat16(acc * dd);
}

// Last hidden conv fused with 64->1 matmul: zg[d] = (relu(dd*sum+b) . Wout) * dd.
__global__ __launch_bounds__(TPB) void k_gconv_z(
    const bf16* __restrict__ gIn, const float* __restrict__ dinv,
    const int* __restrict__ row_start, const unsigned short* __restrict__ bucket,
    const float* __restrict__ bias, const float* __restrict__ Wout,
    float* __restrict__ zg, int n, int E) {
    __shared__ float sVp[4][4 * 64];
    int tid = threadIdx.x;
    int r = tid >> 6, j = tid & 63;
    int d = blockIdx.x * 4 + r;
    if (d >= n) return;                   // wave-uniform
    float dd = dinv[d];
    int k0 = row_start[d], k1 = row_start[d + 1];
    k1 = min(k1, E); k0 = max(min(k0, k1), 0);
    agg_row_quad(gIn, bucket, k0, k1, d, sVp[r], j, (unsigned)(n - 1), (unsigned)(E - 1));
    float v = sVp[r][j] + sVp[r][64 + j] + sVp[r][128 + j] + sVp[r][192 + j];
    float a = fmaxf(fmaf(dd, v, bias[j]), 0.f) * Wout[j];
#pragma unroll
    for (int off = 32; off > 0; off >>= 1) a += __shfl_down(a, off);
    if (j == 0) zg[d] = a * dd;
}

// out[d] = dd*(zg[d] + sum zg[s]) + b_out.  One wave per node, lane = neighbor.
__global__ __launch_bounds__(TPB) void k_out(
    const float* __restrict__ zg, const float* __restrict__ dinv,
    const int* __restrict__ row_start, const unsigned short* __restrict__ bucket,
    const float* __restrict__ b_out, float* __restrict__ out, int n, int E) {
    int t = blockIdx.x * blockDim.x + threadIdx.x;
    int d = t >> 6, lane = t & 63;
    if (d >= n) return;
    int k0 = row_start[d], k1 = row_start[d + 1];
    k1 = min(k1, E); k0 = max(min(k0, k1), 0);
    unsigned nm1 = (unsigned)(n - 1);
    float v = 0.f;
    for (int k = k0 + lane; k < k1; k += 64) {
        unsigned s = min((unsigned)bucket[k], nm1);
        v += zg[s];
    }
#pragma unroll
    for (int off = 32; off > 0; off >>= 1) v += __shfl_down(v, off);
    if (lane == 0) out[d] = fmaf(zg[d] + v, dinv[d], b_out[0]);
}

extern "C" void kernel_launch(void* const* d_in, const int* in_sizes, int n_in,
                              void* d_out, int out_size, void* d_ws, size_t ws_size,
                              hipStream_t stream) {
    const float* x     = (const float*)d_in[0];
    const int*   ei    = (const int*)d_in[1];
    const float* W_in  = (const float*)d_in[2];
    const float* b_in  = (const float*)d_in[3];
    const float* W_h   = (const float*)d_in[4];
    const float* b_h   = (const float*)d_in[5];
    const float* W_out = (const float*)d_in[6];
    const float* b_out = (const float*)d_in[7];
    float* out = (float*)d_out;

    int N = in_sizes[0] / 4;
    int E = in_sizes[1] / 2;
    const int* src = ei;
    const int* dst = ei + E;

    char* ws = (char*)d_ws;
    bf16* gA               = (bf16*)ws;           ws += (size_t)N * 64 * 2;
    bf16* gB               = (bf16*)ws;           ws += (size_t)N * 64 * 2;
    unsigned short* bucket = (unsigned short*)ws; ws += (size_t)E * 2;
    unsigned* staging      = (unsigned*)ws;       ws += (size_t)E * 4;
    int*  row_start        = (int*)ws;            ws += (size_t)(N + 1) * 4;
    int*  cursor           = (int*)ws;            ws += (size_t)N * 4;
    int*  cnt              = (int*)ws;            ws += (size_t)N * 4;
    float* dinv            = (float*)ws;          ws += (size_t)N * 4;
    float* zg              = (float*)ws;          ws += (size_t)N * 4;
    int*  bsum             = (int*)ws;            ws += 257 * 4;
    int*  bcur             = (int*)ws;            // 256 ints

    int B   = (N + 255) >> 8;            // dst buckets (196 for N=50000; <=256)
    int gN  = (N + TPB - 1) / TPB;       // scan chunk count (<=256 for N<=65536)
    int gE  = (E + TPB - 1) / TPB;
    int gNF = (N * 64 + TPB - 1) / TPB;
    int gN4 = (N + 3) / 4;               // 4 nodes/block (1 wave per node)
    int gBin = (E + CHUNK - 1) / CHUNK;  // 391

    // ---- CSR build + norms ----
    k_zero_cnt<<<gN, TPB, 0, stream>>>(cnt, N);
    k_hist<<<gE, TPB, 0, stream>>>(dst, cnt, E, N);
    k_blocksum<<<gN, TPB, 0, stream>>>(cnt, bsum, N);
    k_scan_bsum<<<1, TPB, 0, stream>>>(bsum, gN);
    k_scan_final<<<gN, TPB, 0, stream>>>(cnt, bsum, row_start, cursor, dinv, N);
    k_init_bcur<<<1, TPB, 0, stream>>>(row_start, bcur, B, N);
    k_bin<<<gBin, TPB, 0, stream>>>(src, dst, bcur, staging, E, N);
    k_unbin<<<B, TPB, 0, stream>>>(staging, row_start, cursor, bucket, E, N);

    // ---- layers (feature buffers premultiplied by dinv) ----
    k_mm_in<<<gNF, TPB, 0, stream>>>(x, W_in, dinv, gA, N);
    k_gconv<<<gN4, TPB, 0, stream>>>(gA, dinv, row_start, bucket, b_in, W_h, gB, N, E);
    k_gconv<<<gN4, TPB, 0, stream>>>(gB, dinv, row_start, bucket, b_h, W_h + 4096, gA, N, E);
    k_gconv<<<gN4, TPB, 0, stream>>>(gA, dinv, row_start, bucket, b_h + 64, W_h + 8192, gB, N, E);
    k_gconv_z<<<gN4, TPB, 0, stream>>>(gB, dinv, row_start, bucket, b_h + 128, W_out, zg, N, E);
    k_out<<<gN4, TPB, 0, stream>>>(zg, dinv, row_start, bucket, b_out, out, N, E);
}

// Round 15
// 273.467 us; speedup vs baseline: 1.3156x; 1.1350x over previous
//
#include <hip/hip_runtime.h>
#include <hip/hip_bf16.h>

// GCN: N=50000, E=800000, hidden 64, 5 convs (relu on first 4).
// f32 tensors, int32 edge_index, f32 d_out[N].  ws_size in [19.8, 26.0) MB.
// r12-r14 established: gather layers plateau at ~44us regardless of occupancy/
// barriers/W-placement (per-CU scattered-line service saturation; random graph =>
// no locality). Remaining slack is the CSR build (~55-60us over 6 dispatches).
// This round: bucket-centric CSR build —
//   k_bktcnt (LDS hist over dst>>8, 196 global atomics/block)
//   k_bktscan (1-block scan -> bucket bases/cursors)
//   k_bin     (unchanged: reserve + staged run writes)
//   k_unbin2  (block per bucket: per-node hist+prefix in LDS -> row_start, dinv,
//              record placement via LDS cursors)
// Deletes k_zero_cnt/k_hist/k_blocksum/k_scan_bsum/k_scan_final and all global
// per-node cursor atomics. Layer kernels identical to round 14.
// Workspace (~18.2 MB): gA bf16[N*64] | gB bf16[N*64] | bucket u16[E] | staging u32[E]
//   | row_start i32[N+1] | dinv f32[N] | zg f32[N] | bktcnt i32[256] | bktbase i32[257]
//   | bcur i32[256]

#define TPB 256
#define EPT 8                    // edges per thread in k_bin / k_bktcnt
#define CHUNK (TPB * EPT)        // 2048 edges per block
typedef __hip_bfloat16 bf16;
#define B2F __bfloat162float

__global__ void k_zero_b(int* __restrict__ bktcnt) {
    bktcnt[threadIdx.x] = 0;
}

// Per-bucket (dst>>8) edge counts via LDS histogram.
__global__ __launch_bounds__(TPB) void k_bktcnt(
    const int* __restrict__ dst, int* __restrict__ bktcnt, int E, int n) {
    __shared__ int h[256];
    int tid = threadIdx.x;
    h[tid] = 0;
    __syncthreads();
    int e0 = blockIdx.x * CHUNK;
#pragma unroll
    for (int u = 0; u < EPT; ++u) {
        int e = e0 + u * TPB + tid;
        if (e < E) {
            int d = dst[e];
            if ((unsigned)d < (unsigned)n) atomicAdd(&h[d >> 8], 1);
        }
    }
    __syncthreads();
    if (h[tid]) atomicAdd(&bktcnt[tid], h[tid]);
}

// Exclusive scan of 256 bucket counts -> bktbase[257]; bcur = bktbase copy.
__global__ void k_bktscan(const int* __restrict__ bktcnt, int* __restrict__ bktbase,
                          int* __restrict__ bcur) {
    __shared__ int s[256];
    int t = threadIdx.x;
    int v = bktcnt[t];
    s[t] = v;
    __syncthreads();
    for (int off = 1; off < 256; off <<= 1) {
        int u = (t >= off) ? s[t - off] : 0;
        __syncthreads();
        s[t] += u;
        __syncthreads();
    }
    int excl = s[t] - v;
    bktbase[t] = excl;
    bcur[t] = excl;
    if (t == 255) bktbase[256] = s[t];
}

// Pass 1: bin edges by dst>>8 into staging (record = src | (dst&255)<<16).
__global__ __launch_bounds__(TPB) void k_bin(
    const int* __restrict__ src, const int* __restrict__ dst,
    int* __restrict__ bcur, unsigned* __restrict__ staging, int E, int n) {
    __shared__ int hcnt[256];
    __shared__ int hbase[256];
    int tid = threadIdx.x;
    int e0 = blockIdx.x * CHUNK;
    hcnt[tid] = 0;
    __syncthreads();

    int eb[EPT];
    unsigned rec[EPT];
#pragma unroll
    for (int u = 0; u < EPT; ++u) {
        int e = e0 + u * TPB + tid;
        eb[u] = -1;
        if (e < E) {
            int d = dst[e], s = src[e];
            if ((unsigned)d < (unsigned)n && (unsigned)s < (unsigned)n) {
                eb[u] = d >> 8;
                rec[u] = (unsigned)s | ((unsigned)(d & 255) << 16);
                atomicAdd(&hcnt[eb[u]], 1);
            }
        }
    }
    __syncthreads();
    int c = hcnt[tid];
    hbase[tid] = (c > 0) ? atomicAdd(&bcur[tid], c) : 0;
    hcnt[tid] = 0;
    __syncthreads();
#pragma unroll
    for (int u = 0; u < EPT; ++u) {
        if (eb[u] >= 0) {
            int r = atomicAdd(&hcnt[eb[u]], 1);
            int pos = hbase[eb[u]] + r;
            if ((unsigned)pos < (unsigned)E) staging[pos] = rec[u];  // replay-safe
        }
    }
}

// Pass 2: one block per bucket. Per-node histogram + prefix in LDS -> row_start,
// dinv, and record placement via LDS cursors (no global per-node atomics).
__global__ __launch_bounds__(TPB) void k_unbin2(
    const unsigned* __restrict__ staging, const int* __restrict__ bktbase,
    int* __restrict__ row_start, float* __restrict__ dinv,
    unsigned short* __restrict__ bucket, int E, int n) {
    __shared__ int cnt[256];
    __shared__ int scn[256];
    __shared__ int cur[256];
    int b = blockIdx.x, tid = threadIdx.x;
    int lo = bktbase[b], hi = bktbase[b + 1];
    lo = max(0, min(lo, E)); hi = max(lo, min(hi, E));

    cnt[tid] = 0;
    __syncthreads();
    for (int i = lo + tid; i < hi; i += TPB)
        atomicAdd(&cnt[(staging[i] >> 16) & 255], 1);
    __syncthreads();

    int v = cnt[tid];
    scn[tid] = v;
    __syncthreads();
    for (int off = 1; off < 256; off <<= 1) {
        int u = (tid >= off) ? scn[tid - off] : 0;
        __syncthreads();
        scn[tid] += u;
        __syncthreads();
    }
    int excl = scn[tid] - v;
    int base = min(lo + excl, E);
    cur[tid] = base;
    int d = (b << 8) + tid;
    if (d < n) {
        row_start[d] = base;
        dinv[d] = rsqrtf((float)v + 1.0f);     // +1 self-loop
        if (d == n - 1) row_start[n] = min(base + v, E);
    }
    __syncthreads();

    for (int i = lo + tid; i < hi; i += TPB) {
        unsigned r = staging[i];
        int t = (r >> 16) & 255;
        int pos = atomicAdd(&cur[t], 1);
        if ((unsigned)pos < (unsigned)E) bucket[pos] = (unsigned short)(r & 0xffffu);
    }
}

// g1[i][j] = (sum_{k<4} x[i][k] * W_in[k][j]) * dinv[i]   (premultiplied)
__global__ void k_mm_in(const float* __restrict__ x, const float* __restrict__ W,
                        const float* __restrict__ dinv, bf16* __restrict__ g, int n) {
    int t = blockIdx.x * blockDim.x + threadIdx.x;
    if (t >= n * 64) return;
    int i = t >> 6, j = t & 63;
    float acc = 0.f;
#pragma unroll
    for (int k = 0; k < 4; ++k) acc = fmaf(x[i * 4 + k], W[k * 64 + j], acc);
    g[t] = __float2bfloat16(acc * dinv[i]);
}

__device__ __forceinline__ void acc_quad(float4& a, uint2 w) {
    a.x += __uint_as_float(w.x << 16);
    a.y += __uint_as_float(w.x & 0xffff0000u);
    a.z += __uint_as_float(w.y << 16);
    a.w += __uint_as_float(w.y & 0xffff0000u);
}

// Quad gather: 4 edges per load instruction; lane group g=lane>>4 takes edge k+g,
// lane i=lane&15 loads uint2 = 4 packed bf16 feats. Each group writes its float4
// partial to its own LDS row; the (same-wave) transform sums the 4 rows.
__device__ __forceinline__ void agg_row_quad(const bf16* __restrict__ g,
                                             const unsigned short* __restrict__ bucket,
                                             int k0, int k1, int d, float* __restrict__ sVp,
                                             int lane, unsigned nm1, unsigned Em1) {
    int grp = lane >> 4, i = lane & 15;
    float4 a = {0.f, 0.f, 0.f, 0.f};
    if (grp == 0) {  // self term
        uint2 w = *(const uint2*)(g + (size_t)d * 64 + 4 * i);
        acc_quad(a, w);
    }
    for (int base = k0; base < k1; base += 64) {
        int cnt = min(64, k1 - base);
        int rec = bucket[min((unsigned)(base + lane), Em1)];  // coalesced u16 load
        int k = 0;
        for (; k + 16 <= cnt; k += 16) {                      // 16 edges, 4 quad loads
            unsigned s0 = min((unsigned)__shfl(rec, k + 0 + grp), nm1);
            unsigned s1 = min((unsigned)__shfl(rec, k + 4 + grp), nm1);
            unsigned s2 = min((unsigned)__shfl(rec, k + 8 + grp), nm1);
            unsigned s3 = min((unsigned)__shfl(rec, k + 12 + grp), nm1);
            uint2 w0 = *(const uint2*)(g + (size_t)s0 * 64 + 4 * i);
            uint2 w1 = *(const uint2*)(g + (size_t)s1 * 64 + 4 * i);
            uint2 w2 = *(const uint2*)(g + (size_t)s2 * 64 + 4 * i);
            uint2 w3 = *(const uint2*)(g + (size_t)s3 * 64 + 4 * i);
            acc_quad(a, w0); acc_quad(a, w1); acc_quad(a, w2); acc_quad(a, w3);
        }
        for (; k < cnt; k += 4) {                             // tail, predicated
            int e = k + grp;
            unsigned s = min((unsigned)__shfl(rec, min(e, 63)), nm1);
            uint2 w = *(const uint2*)(g + (size_t)s * 64 + 4 * i);
            if (e < cnt) acc_quad(a, w);
        }
    }
    ((float4*)(sVp + grp * 64))[i] = a;   // partial row per group (wave-local)
}

// Fused layer: one wave per node (4 nodes/block). No LDS W tile, no barriers:
// W read from global (L1-resident); sVp wave-local.
__global__ __launch_bounds__(TPB) void k_gconv(
    const bf16* __restrict__ gIn, const float* __restrict__ dinv,
    const int* __restrict__ row_start, const unsigned short* __restrict__ bucket,
    const float* __restrict__ bias, const float* __restrict__ W,
    bf16* __restrict__ gOut, int n, int E) {
    __shared__ float sVp[4][4 * 64];     // [wave][group][64]
    int tid = threadIdx.x;
    int r = tid >> 6, j = tid & 63;
    int d = blockIdx.x * 4 + r;
    if (d >= n) return;                   // wave-uniform
    float dd = dinv[d];
    int k0 = row_start[d], k1 = row_start[d + 1];
    k1 = min(k1, E); k0 = max(min(k0, k1), 0);
    agg_row_quad(gIn, bucket, k0, k1, d, sVp[r], j, (unsigned)(n - 1), (unsigned)(E - 1));
    float v = sVp[r][j] + sVp[r][64 + j] + sVp[r][128 + j] + sVp[r][192 + j];
    float a = fmaxf(fmaf(dd, v, bias[j]), 0.f);
    sVp[r][j] = a;                        // row 0 holds the activation (wave-local)
    const float4* ap = (const float4*)&sVp[r][0];
    float acc0 = 0.f, acc1 = 0.f, acc2 = 0.f, acc3 = 0.f;
#pragma unroll
    for (int k4 = 0; k4 < 16; ++k4) {
        float4 a4 = ap[k4];               // wave-uniform address -> broadcast b128
        acc0 = fmaf(a4.x, W[(4 * k4 + 0) * 64 + j], acc0);
        acc1 = fmaf(a4.y, W[(4 * k4 + 1) * 64 + j], acc1);
        acc2 = fmaf(a4.z, W[(4 * k4 + 2) * 64 + j], acc2);
        acc3 = fmaf(a4.w, W[(4 * k4 + 3) * 64 + j], acc3);
    }
    float acc = (acc0 + acc1) + (acc2 + acc3);
    gOut[(size_t)d * 64 + j] = __float2bfloat16(acc * dd);
}

// Last hidden conv fused with 64->1 matmul: zg[d] = (relu(dd*sum+b) . Wout) * dd.
__global__ __launch_bounds__(TPB) void k_gconv_z(
    const bf16* __restrict__ gIn, const float* __restrict__ dinv,
    const int* __restrict__ row_start, const unsigned short* __restrict__ bucket,
    const float* __restrict__ bias, const float* __restrict__ Wout,
    float* __restrict__ zg, int n, int E) {
    __shared__ float sVp[4][4 * 64];
    int tid = threadIdx.x;
    int r = tid >> 6, j = tid & 63;
    int d = blockIdx.x * 4 + r;
    if (d >= n) return;                   // wave-uniform
    float dd = dinv[d];
    int k0 = row_start[d], k1 = row_start[d + 1];
    k1 = min(k1, E); k0 = max(min(k0, k1), 0);
    agg_row_quad(gIn, bucket, k0, k1, d, sVp[r], j, (unsigned)(n - 1), (unsigned)(E - 1));
    float v = sVp[r][j] + sVp[r][64 + j] + sVp[r][128 + j] + sVp[r][192 + j];
    float a = fmaxf(fmaf(dd, v, bias[j]), 0.f) * Wout[j];
#pragma unroll
    for (int off = 32; off > 0; off >>= 1) a += __shfl_down(a, off);
    if (j == 0) zg[d] = a * dd;
}

// out[d] = dd*(zg[d] + sum zg[s]) + b_out.  One wave per node, lane = neighbor.
__global__ __launch_bounds__(TPB) void k_out(
    const float* __restrict__ zg, const float* __restrict__ dinv,
    const int* __restrict__ row_start, const unsigned short* __restrict__ bucket,
    const float* __restrict__ b_out, float* __restrict__ out, int n, int E) {
    int t = blockIdx.x * blockDim.x + threadIdx.x;
    int d = t >> 6, lane = t & 63;
    if (d >= n) return;
    int k0 = row_start[d], k1 = row_start[d + 1];
    k1 = min(k1, E); k0 = max(min(k0, k1), 0);
    unsigned nm1 = (unsigned)(n - 1);
    float v = 0.f;
    for (int k = k0 + lane; k < k1; k += 64) {
        unsigned s = min((unsigned)bucket[k], nm1);
        v += zg[s];
    }
#pragma unroll
    for (int off = 32; off > 0; off >>= 1) v += __shfl_down(v, off);
    if (lane == 0) out[d] = fmaf(zg[d] + v, dinv[d], b_out[0]);
}

extern "C" void kernel_launch(void* const* d_in, const int* in_sizes, int n_in,
                              void* d_out, int out_size, void* d_ws, size_t ws_size,
                              hipStream_t stream) {
    const float* x     = (const float*)d_in[0];
    const int*   ei    = (const int*)d_in[1];
    const float* W_in  = (const float*)d_in[2];
    const float* b_in  = (const float*)d_in[3];
    const float* W_h   = (const float*)d_in[4];
    const float* b_h   = (const float*)d_in[5];
    const float* W_out = (const float*)d_in[6];
    const float* b_out = (const float*)d_in[7];
    float* out = (float*)d_out;

    int N = in_sizes[0] / 4;
    int E = in_sizes[1] / 2;
    const int* src = ei;
    const int* dst = ei + E;

    char* ws = (char*)d_ws;
    bf16* gA               = (bf16*)ws;           ws += (size_t)N * 64 * 2;
    bf16* gB               = (bf16*)ws;           ws += (size_t)N * 64 * 2;
    unsigned short* bucket = (unsigned short*)ws; ws += (size_t)E * 2;
    unsigned* staging      = (unsigned*)ws;       ws += (size_t)E * 4;
    int*  row_start        = (int*)ws;            ws += (size_t)(N + 1) * 4;
    float* dinv            = (float*)ws;          ws += (size_t)N * 4;
    float* zg              = (float*)ws;          ws += (size_t)N * 4;
    int*  bktcnt           = (int*)ws;            ws += 256 * 4;
    int*  bktbase          = (int*)ws;            ws += 257 * 4;
    int*  bcur             = (int*)ws;            // 256 ints

    int B   = (N + 255) >> 8;            // dst buckets (196 for N=50000; <=256)
    int gNF = (N * 64 + TPB - 1) / TPB;
    int gN4 = (N + 3) / 4;               // 4 nodes/block (1 wave per node)
    int gBin = (E + CHUNK - 1) / CHUNK;  // 391

    // ---- CSR build + norms (bucket-centric) ----
    k_zero_b<<<1, 256, 0, stream>>>(bktcnt);
    k_bktcnt<<<gBin, TPB, 0, stream>>>(dst, bktcnt, E, N);
    k_bktscan<<<1, 256, 0, stream>>>(bktcnt, bktbase, bcur);
    k_bin<<<gBin, TPB, 0, stream>>>(src, dst, bcur, staging, E, N);
    k_unbin2<<<B, TPB, 0, stream>>>(staging, bktbase, row_start, dinv, bucket, E, N);

    // ---- layers (feature buffers premultiplied by dinv) ----
    k_mm_in<<<gNF, TPB, 0, stream>>>(x, W_in, dinv, gA, N);
    k_gconv<<<gN4, TPB, 0, stream>>>(gA, dinv, row_start, bucket, b_in, W_h, gB, N, E);
    k_gconv<<<gN4, TPB, 0, stream>>>(gB, dinv, row_start, bucket, b_h, W_h + 4096, gA, N, E);
    k_gconv<<<gN4, TPB, 0, stream>>>(gA, dinv, row_start, bucket, b_h + 64, W_h + 8192, gB, N, E);
    k_gconv_z<<<gN4, TPB, 0, stream>>>(gB, dinv, row_start, bucket, b_h + 128, W_out, zg, N, E);
    k_out<<<gN4, TPB, 0, stream>>>(zg, dinv, row_start, bucket, b_out, out, N, E);
}